// Round 3
// baseline (553.148 us; speedup 1.0000x reference)
//
#include <hip/hip_runtime.h>
#include <stdint.h>
#include <stddef.h>

// ---------------------------------------------------------------------------
// CausalSelfAttention forward, MI355X/gfx950.
// Pipeline: cvt(fp32->bf16) -> GEMM1(qkv) -> norm+rope+transpose ->
//           attn_split (flash, fixed-max softmax, 2-way key split) ->
//           attn_reduce -> GEMM2(out proj, fp32)
// R3: split-K attention. Fixed-max softmax => partials combine additively
//     (no rescale), so key-split needs only a cheap reduce pass.
//     8192 waves (32/CU) vs R2's 2048 (8/CU) - kills the latency bound.
// ---------------------------------------------------------------------------

typedef __attribute__((ext_vector_type(8))) __bf16 bf16x8;
typedef __attribute__((ext_vector_type(4))) __bf16 bf16x4;
typedef __attribute__((ext_vector_type(4))) float  f32x4;

#define NB 2
#define NT 2048
#define NC 1536
#define NH 16
#define ND 96
#define NQKV 4608          // 3*NC
#define NM 4096            // NB*NT

static __device__ __forceinline__ float fexp2(float x) {
#if __has_builtin(__builtin_amdgcn_exp2f)
  return __builtin_amdgcn_exp2f(x);
#else
  return exp2f(x);
#endif
}

// async global->LDS, 16B per lane; LDS dest = wave-uniform base + lane*16
static __device__ __forceinline__ void g2lds16(const void* g, void* l) {
  __builtin_amdgcn_global_load_lds(
      (const __attribute__((address_space(1))) void*)g,
      (__attribute__((address_space(3))) void*)l, 16, 0, 0);
}

// ---------------------------------------------------------------------------
// fp32 -> bf16 conversion (vectorized 4-wide)
// ---------------------------------------------------------------------------
__global__ __launch_bounds__(256) void cvt_f32_bf16(
    const float4* __restrict__ src, bf16x4* __restrict__ dst, int n4) {
  int i = blockIdx.x * 256 + threadIdx.x;
  if (i < n4) {
    float4 v = src[i];
    bf16x4 o;
    o[0] = (__bf16)v.x; o[1] = (__bf16)v.y;
    o[2] = (__bf16)v.z; o[3] = (__bf16)v.w;
    dst[i] = o;
  }
}

// ---------------------------------------------------------------------------
// GEMM: C[m][n] = sum_k A[m][k] * B[n][k]   (A: MxK bf16, B: NxK bf16)
// 128x128 tile, BK=32, 4 waves (2x2), each wave 64x64 via 4x4 mfma 16x16x32.
// ---------------------------------------------------------------------------
__global__ __launch_bounds__(256) void gemm_bt(
    const __bf16* __restrict__ A, const __bf16* __restrict__ Bw,
    float* __restrict__ Cf, __bf16* __restrict__ Cb, int M, int N, int K) {
  __shared__ __align__(16) __bf16 Al[128 * 32];
  __shared__ __align__(16) __bf16 Bl[128 * 32];
  const int tid = threadIdx.x;
  const int l   = tid & 63;
  const int w   = tid >> 6;
  const int m0  = blockIdx.y * 128;
  const int n0  = blockIdx.x * 128;
  const int wm  = (w >> 1) * 64;
  const int wn  = (w & 1) * 64;
  const int lm  = l & 15;
  const int lq  = l >> 4;
  const int srow = l >> 2;          // row within wave chunk
  const int scol = (l & 3) * 8;     // bf16 element offset in row

  f32x4 acc[4][4] = {};

  for (int k0 = 0; k0 < K; k0 += 32) {
#pragma unroll
    for (int rd = 0; rd < 2; ++rd) {
      const int row = rd * 64 + w * 16 + srow;
      const int lof = rd * 4096 + w * 1024;
      g2lds16(A  + (size_t)(m0 + row) * K + k0 + scol, (char*)Al + lof);
      g2lds16(Bw + (size_t)(n0 + row) * K + k0 + scol, (char*)Bl + lof);
    }
    __syncthreads();
    bf16x8 af[4], bfr[4];
#pragma unroll
    for (int mi = 0; mi < 4; ++mi)
      af[mi] = *(const bf16x8*)(Al + (wm + mi * 16 + lm) * 32 + lq * 8);
#pragma unroll
    for (int ni = 0; ni < 4; ++ni)
      bfr[ni] = *(const bf16x8*)(Bl + (wn + ni * 16 + lm) * 32 + lq * 8);
#pragma unroll
    for (int mi = 0; mi < 4; ++mi)
#pragma unroll
      for (int ni = 0; ni < 4; ++ni)
        acc[mi][ni] = __builtin_amdgcn_mfma_f32_16x16x32_bf16(
            af[mi], bfr[ni], acc[mi][ni], 0, 0, 0);
    __syncthreads();
  }

  // epilogue: C/D layout col=lane&15, row=(lane>>4)*4+r  (m89/m91 verified)
  const int r0 = lq * 4;
#pragma unroll
  for (int mi = 0; mi < 4; ++mi)
#pragma unroll
    for (int ni = 0; ni < 4; ++ni)
#pragma unroll
      for (int r = 0; r < 4; ++r) {
        const size_t row = (size_t)(m0 + wm + mi * 16 + r0 + r);
        const size_t col = (size_t)(n0 + wn + ni * 16 + lm);
        if (Cf) Cf[row * N + col] = acc[mi][ni][r];
        else    Cb[row * N + col] = (__bf16)acc[mi][ni][r];
      }
}

// ---------------------------------------------------------------------------
// qk RMS-norm + 3D RoPE + layout transform.
// ---------------------------------------------------------------------------
static __device__ __forceinline__ float rope_one(float v, float p, int d,
                                                 const float* c3) {
  const int a  = d >> 5;        // which of 3 coord axes (d3=32)
  const int j  = d & 31;
  const int jj = j & 15;        // half=16
  const float invf = fexp2((float)jj * -0.8304820237218406f);
  const float ang  = c3[a] * invf;
  float sn, cs;
  __sincosf(ang, &sn, &cs);
  return (j < 16) ? (v * cs - p * sn) : (v * cs + p * sn);
}

__global__ __launch_bounds__(256) void normrope_kernel(
    const __bf16* __restrict__ qkv, const float* __restrict__ coords,
    const int* __restrict__ ttype, const float* __restrict__ qsc,
    const float* __restrict__ ksc, __bf16* __restrict__ qo,
    __bf16* __restrict__ ko, __bf16* __restrict__ vo) {
  const int l   = threadIdx.x & 63;
  const int w   = threadIdx.x >> 6;
  const int rid = blockIdx.x * 4 + w;       // (b*T+t)*H + h
  const int h   = rid & (NH - 1);
  const int bt  = rid >> 4;
  const int t   = bt & (NT - 1);
  const int b   = bt >> 11;                 // T = 2048
  const __bf16* base = qkv + (size_t)bt * NQKV + h * ND;
  const float*  c3   = coords + (size_t)bt * 3;
  const bool rope    = ttype[bt] > 0;
  const size_t bh    = (size_t)(b * NH + h);

  // ---- q ----
  {
    float x0 = (float)base[l];
    float x1 = (l < 32) ? (float)base[64 + l] : 0.f;
    float ss = x0 * x0 + x1 * x1;
#pragma unroll
    for (int off = 1; off < 64; off <<= 1) ss += __shfl_xor(ss, off, 64);
    const float rn = rsqrtf(ss * (1.f / 96.f) + 1e-6f);
    x0 *= rn * qsc[l];
    if (l < 32) x1 *= rn * qsc[64 + l];
    const float p0 = __shfl_xor(x0, 16, 64);
    const float p1 = __shfl_xor(x1, 16, 64);
    if (rope) {
      x0 = rope_one(x0, p0, l, c3);
      if (l < 32) x1 = rope_one(x1, p1, 64 + l, c3);
    }
    __bf16* dst = qo + (bh * NT + t) * ND;
    dst[l] = (__bf16)x0;
    if (l < 32) dst[64 + l] = (__bf16)x1;
  }
  // ---- k ----
  {
    float x0 = (float)base[NC + l];
    float x1 = (l < 32) ? (float)base[NC + 64 + l] : 0.f;
    float ss = x0 * x0 + x1 * x1;
#pragma unroll
    for (int off = 1; off < 64; off <<= 1) ss += __shfl_xor(ss, off, 64);
    const float rn = rsqrtf(ss * (1.f / 96.f) + 1e-6f);
    x0 *= rn * ksc[l];
    if (l < 32) x1 *= rn * ksc[64 + l];
    const float p0 = __shfl_xor(x0, 16, 64);
    const float p1 = __shfl_xor(x1, 16, 64);
    if (rope) {
      x0 = rope_one(x0, p0, l, c3);
      if (l < 32) x1 = rope_one(x1, p1, 64 + l, c3);
    }
    __bf16* dst = ko + (bh * NT + t) * ND;
    dst[l] = (__bf16)x0;
    if (l < 32) dst[64 + l] = (__bf16)x1;
  }
  // ---- v (transpose only) ----
  {
    vo[(bh * ND + l) * NT + t] = base[2 * NC + l];
    if (l < 32) vo[(bh * ND + 64 + l) * NT + t] = base[2 * NC + 64 + l];
  }
}

// ---------------------------------------------------------------------------
// Split-K flash attention, fixed-max softmax.
// q,k: (B,H,T,D) bf16; vT: (B,H,D,T) bf16.
// Grid (32, B*H, 2): x = q-tile (descending work order), z = key split.
// Wave = one 16-row q-frag; split z handles key-tiles kt = z, z+2, ...
// Partials: Oz fp32 (B*T, C) layout, Lz fp32 (bh, t). Fixed max (|q.k|<=96
// after RMS-norm) => partials combine by plain addition in attn_reduce.
// ---------------------------------------------------------------------------
static __device__ __forceinline__ void attn_tile(
    const bf16x8 (&aq)[3], const bf16x8 (&bk)[2][3], int q0r, int n0,
    int lm, int lq, f32x4& lsum, __bf16* pbase /* 16 rows x 40 */) {
  f32x4 s[2];
#pragma unroll
  for (int nt = 0; nt < 2; ++nt) {
    f32x4 a = {};
#pragma unroll
    for (int c = 0; c < 3; ++c)
      a = __builtin_amdgcn_mfma_f32_16x16x32_bf16(aq[c], bk[nt][c], a, 0, 0, 0);
    s[nt] = a;
  }
  if (n0 + 31 > q0r) {   // diagonal-straddling tile: causal mask
#pragma unroll
    for (int nt = 0; nt < 2; ++nt)
#pragma unroll
      for (int r = 0; r < 4; ++r)
        if (n0 + nt * 16 + lm > q0r + lq * 4 + r) s[nt][r] = -1e30f;
  }
  const float cl = 0.10206207261596575f * 1.4426950408889634f;
#pragma unroll
  for (int nt = 0; nt < 2; ++nt)
#pragma unroll
    for (int r = 0; r < 4; ++r)
      s[nt][r] = fexp2((s[nt][r] - 96.0f) * cl);
#pragma unroll
  for (int r = 0; r < 4; ++r) lsum[r] += s[0][r] + s[1][r];
#pragma unroll
  for (int nt = 0; nt < 2; ++nt)
#pragma unroll
    for (int r = 0; r < 4; ++r)
      pbase[(lq * 4 + r) * 40 + nt * 16 + lm] = (__bf16)s[nt][r];
}

__global__ __launch_bounds__(256) void attn_split(
    const __bf16* __restrict__ q, const __bf16* __restrict__ k,
    const __bf16* __restrict__ vt, float* __restrict__ O0,
    float* __restrict__ O1, float* __restrict__ L0,
    float* __restrict__ L1) {
  __shared__ __align__(16) __bf16 plds[4][16][40];
  const int tid = threadIdx.x;
  const int l   = tid & 63;
  const int w   = tid >> 6;
  const int bh  = blockIdx.y;
  const int z   = blockIdx.z;
  const int qt  = 31 - blockIdx.x;          // big (most-keys) tiles first
  const int q0  = qt * 64 + w * 16;
  const int lm  = l & 15;
  const int lq  = l >> 4;
  float* __restrict__ Oz = z ? O1 : O0;
  float* __restrict__ Lz = z ? L1 : L0;
  const __bf16* qh = q  + (size_t)bh * NT * ND;
  const __bf16* kh = k  + (size_t)bh * NT * ND;
  const __bf16* vh = vt + (size_t)bh * ND * NT;
  __bf16* pb = &plds[w][0][0];

  bf16x8 aq[3];
#pragma unroll
  for (int c = 0; c < 3; ++c)
    aq[c] = *(const bf16x8*)(qh + (size_t)(q0 + lm) * ND + c * 32 + lq * 8);

  f32x4 o[6] = {};
  f32x4 ls = {};
  const int nkt = ((q0 + 15) >> 5) + 1;

  for (int kt = z; kt < nkt; kt += 2) {
    const int n0 = kt * 32;
    bf16x8 bk[2][3];
#pragma unroll
    for (int nt = 0; nt < 2; ++nt)
#pragma unroll
      for (int c = 0; c < 3; ++c)
        bk[nt][c] = *(const bf16x8*)(kh + (size_t)(n0 + nt * 16 + lm) * ND +
                                     c * 32 + lq * 8);
    attn_tile(aq, bk, q0, n0, lm, lq, ls, pb);
    bf16x8 ap = *(const bf16x8*)(pb + lm * 40 + lq * 8);
#pragma unroll
    for (int dt = 0; dt < 6; ++dt) {
      bf16x8 bv = *(const bf16x8*)(vh + (size_t)(dt * 16 + lm) * NT + n0 + lq * 8);
      o[dt] = __builtin_amdgcn_mfma_f32_16x16x32_bf16(ap, bv, o[dt], 0, 0, 0);
    }
  }

  // epilogue: reduce l across the 16 column-lanes, write partials
  const int b = bh >> 4, h = bh & 15;
#pragma unroll
  for (int r = 0; r < 4; ++r) {
    float v = ls[r];
#pragma unroll
    for (int off = 1; off < 16; off <<= 1) v += __shfl_xor(v, off, 64);
    if (lm == 0) Lz[(bh << 11) + q0 + lq * 4 + r] = v;
  }
#pragma unroll
  for (int dt = 0; dt < 6; ++dt)
#pragma unroll
    for (int r = 0; r < 4; ++r) {
      const int t = q0 + lq * 4 + r;
      Oz[((size_t)(b * NT + t)) * NC + h * ND + dt * 16 + lm] = o[dt][r];
    }
}

// ---------------------------------------------------------------------------
// Combine split partials: out = (O0+O1) / (L0+L1), bf16.
// One thread per 4 output elements (never crosses a head boundary: 96%4==0).
// ---------------------------------------------------------------------------
__global__ __launch_bounds__(256) void attn_reduce(
    const float4* __restrict__ O0, const float4* __restrict__ O1,
    const float* __restrict__ L0, const float* __restrict__ L1,
    bf16x4* __restrict__ out) {
  const int i   = blockIdx.x * 256 + threadIdx.x;  // 0 .. NM*NC/4
  const int row = i / (NC / 4);                    // b*NT + t
  const int cg  = i - row * (NC / 4);
  const int h   = cg / (ND / 4);                   // cg*4 / 96
  const int bh  = ((row >> 11) << 4) + h;
  const int t   = row & (NT - 1);
  const float li = 1.f / (L0[(bh << 11) + t] + L1[(bh << 11) + t]);
  const float4 a = O0[i];
  const float4 c = O1[i];
  bf16x4 o;
  o[0] = (__bf16)((a.x + c.x) * li);
  o[1] = (__bf16)((a.y + c.y) * li);
  o[2] = (__bf16)((a.z + c.z) * li);
  o[3] = (__bf16)((a.w + c.w) * li);
  out[i] = o;
}

// ---------------------------------------------------------------------------
// workspace layout (bytes). Liveness-based aliasing:
//  [0, 12.58M)   xb        (GEMM1 A)          -> dead after GEMM1 -> O1 (part)
//  [12.58M,26.74M) wqkvb   (GEMM1 B)          -> dead after GEMM1 -> O1/L0/L1
//  [26.74M,31.46M) woutb   (GEMM2 B, live to end)
//  [31.46M,69.21M) qkvb    (GEMM1 out)        -> dead after normrope ->
//                                                O0 [31.46M,56.62M) +
//                                                attnb [56.62M,69.21M)
//  [69.21M,81.79M) qb ; [81.79M,94.37M) kb ; [94.37M,106.95M) vtb
// ---------------------------------------------------------------------------
static constexpr size_t OFF_XB   = 0;
static constexpr size_t OFF_WQKV = 12582912;
static constexpr size_t OFF_WOUT = 26738688;
static constexpr size_t OFF_QKV  = 31457280;
static constexpr size_t OFF_Q    = 69206016;
static constexpr size_t OFF_K    = 81788928;
static constexpr size_t OFF_VT   = 94371840;   // end 106,954,752
static constexpr size_t OFF_O0   = OFF_QKV;               // 25,165,824 B
static constexpr size_t OFF_ATT  = OFF_QKV + 25165824;    // 12,582,912 B
static constexpr size_t OFF_O1   = 0;                     // 25,165,824 B
static constexpr size_t OFF_L0   = 25165824;              //    262,144 B
static constexpr size_t OFF_L1   = 25428000 - 32;         //    262,144 B (aligned)

extern "C" void kernel_launch(void* const* d_in, const int* in_sizes, int n_in,
                              void* d_out, int out_size, void* d_ws,
                              size_t ws_size, hipStream_t stream) {
  const float* x      = (const float*)d_in[0];
  const float* coords = (const float*)d_in[1];
  const int*   ttype  = (const int*)d_in[2];
  const float* wqkv   = (const float*)d_in[3];
  const float* wout   = (const float*)d_in[4];
  const float* qs     = (const float*)d_in[5];
  const float* ks     = (const float*)d_in[6];

  char* ws = (char*)d_ws;
  __bf16* xb    = (__bf16*)(ws + OFF_XB);
  __bf16* wqkvb = (__bf16*)(ws + OFF_WQKV);
  __bf16* woutb = (__bf16*)(ws + OFF_WOUT);
  __bf16* qkvb  = (__bf16*)(ws + OFF_QKV);
  __bf16* qb    = (__bf16*)(ws + OFF_Q);
  __bf16* kb    = (__bf16*)(ws + OFF_K);
  __bf16* vtb   = (__bf16*)(ws + OFF_VT);
  float*  O0    = (float*)(ws + OFF_O0);
  float*  O1    = (float*)(ws + OFF_O1);
  float*  L0    = (float*)(ws + OFF_L0);
  float*  L1    = (float*)(ws + OFF_L1);
  __bf16* attnb = (__bf16*)(ws + OFF_ATT);

  // 1. fp32 -> bf16 conversions
  {
    const int n4x = NM * NC / 4;            // 1,572,864
    const int n4w = NQKV * NC / 4;          // 1,769,472
    const int n4o = NC * NC / 4;            //   589,824
    cvt_f32_bf16<<<(n4x + 255) / 256, 256, 0, stream>>>(
        (const float4*)x, (bf16x4*)xb, n4x);
    cvt_f32_bf16<<<(n4w + 255) / 256, 256, 0, stream>>>(
        (const float4*)wqkv, (bf16x4*)wqkvb, n4w);
    cvt_f32_bf16<<<(n4o + 255) / 256, 256, 0, stream>>>(
        (const float4*)wout, (bf16x4*)woutb, n4o);
  }
  // 2. qkv = x @ W_qkv^T  (bf16 out)
  gemm_bt<<<dim3(NQKV / 128, NM / 128), 256, 0, stream>>>(
      xb, wqkvb, nullptr, qkvb, NM, NQKV, NC);
  // 3. qk-norm + rope + v-transpose
  normrope_kernel<<<(NB * NT * NH) / 4, 256, 0, stream>>>(
      qkvb, coords, ttype, qs, ks, qb, kb, vtb);
  // 4. split-K causal attention + combine
  attn_split<<<dim3(32, NB * NH, 2), 256, 0, stream>>>(
      qb, kb, vtb, O0, O1, L0, L1);
  attn_reduce<<<(NM * NC / 4) / 256, 256, 0, stream>>>(
      (const float4*)O0, (const float4*)O1, L0, L1, (bf16x4*)attnb);
  // 5. out = attn @ W_out^T (fp32 out)
  gemm_bt<<<dim3(NC / 128, NM / 128), 256, 0, stream>>>(
      attnb, woutb, (float*)d_out, nullptr, NM, NC, NC);
}

// Round 4
// 355.752 us; speedup vs baseline: 1.5549x; 1.5549x over previous
//
#include <hip/hip_runtime.h>
#include <stdint.h>
#include <stddef.h>

// ---------------------------------------------------------------------------
// CausalSelfAttention forward, MI355X/gfx950.
// Pipeline: cvt(fp32->bf16) -> GEMM1(qkv) -> norm+rope+transpose ->
//           attn_fwd2 (flash, fixed-max softmax, LDS-staged K/V) ->
//           GEMM2(out proj, fp32)
// R4: attention is VMEM-demand-bound (~6 TB/s ceiling, measured R1/R2/R3).
//     Block of 8 waves stages each 32-key K/V tile into LDS ONCE via
//     global_load_lds (source-address permutation puts LDS in exact
//     fragment-read order -> conflict-free contiguous ds_read_b128),
//     double-buffered, one barrier/tile, stage issued after the barrier so
//     it overlaps compute. 16 frag-tiles share each staged tile: global
//     traffic per frag-tile drops 6 KB -> 0.75 KB (8x vs R2).
//     Mirrored q-frags (qp and 15-qp) keep per-block work uniform.
// ---------------------------------------------------------------------------

typedef __attribute__((ext_vector_type(8))) __bf16 bf16x8;
typedef __attribute__((ext_vector_type(4))) __bf16 bf16x4;
typedef __attribute__((ext_vector_type(4))) float  f32x4;

#define NB 2
#define NT 2048
#define NC 1536
#define NH 16
#define ND 96
#define NQKV 4608          // 3*NC
#define NM 4096            // NB*NT

static __device__ __forceinline__ float fexp2(float x) {
#if __has_builtin(__builtin_amdgcn_exp2f)
  return __builtin_amdgcn_exp2f(x);
#else
  return exp2f(x);
#endif
}

// async global->LDS, 16B per lane; LDS dest = wave-uniform base + lane*16
static __device__ __forceinline__ void g2lds16(const void* g, void* l) {
  __builtin_amdgcn_global_load_lds(
      (const __attribute__((address_space(1))) void*)g,
      (__attribute__((address_space(3))) void*)l, 16, 0, 0);
}

// ---------------------------------------------------------------------------
// fp32 -> bf16 conversion (vectorized 4-wide)
// ---------------------------------------------------------------------------
__global__ __launch_bounds__(256) void cvt_f32_bf16(
    const float4* __restrict__ src, bf16x4* __restrict__ dst, int n4) {
  int i = blockIdx.x * 256 + threadIdx.x;
  if (i < n4) {
    float4 v = src[i];
    bf16x4 o;
    o[0] = (__bf16)v.x; o[1] = (__bf16)v.y;
    o[2] = (__bf16)v.z; o[3] = (__bf16)v.w;
    dst[i] = o;
  }
}

// ---------------------------------------------------------------------------
// GEMM: C[m][n] = sum_k A[m][k] * B[n][k]   (A: MxK bf16, B: NxK bf16)
// 128x128 tile, BK=32, 4 waves (2x2), each wave 64x64 via 4x4 mfma 16x16x32.
// ---------------------------------------------------------------------------
__global__ __launch_bounds__(256) void gemm_bt(
    const __bf16* __restrict__ A, const __bf16* __restrict__ Bw,
    float* __restrict__ Cf, __bf16* __restrict__ Cb, int M, int N, int K) {
  __shared__ __align__(16) __bf16 Al[128 * 32];
  __shared__ __align__(16) __bf16 Bl[128 * 32];
  const int tid = threadIdx.x;
  const int l   = tid & 63;
  const int w   = tid >> 6;
  const int m0  = blockIdx.y * 128;
  const int n0  = blockIdx.x * 128;
  const int wm  = (w >> 1) * 64;
  const int wn  = (w & 1) * 64;
  const int lm  = l & 15;
  const int lq  = l >> 4;
  const int srow = l >> 2;          // row within wave chunk
  const int scol = (l & 3) * 8;     // bf16 element offset in row

  f32x4 acc[4][4] = {};

  for (int k0 = 0; k0 < K; k0 += 32) {
#pragma unroll
    for (int rd = 0; rd < 2; ++rd) {
      const int row = rd * 64 + w * 16 + srow;
      const int lof = rd * 4096 + w * 1024;
      g2lds16(A  + (size_t)(m0 + row) * K + k0 + scol, (char*)Al + lof);
      g2lds16(Bw + (size_t)(n0 + row) * K + k0 + scol, (char*)Bl + lof);
    }
    __syncthreads();
    bf16x8 af[4], bfr[4];
#pragma unroll
    for (int mi = 0; mi < 4; ++mi)
      af[mi] = *(const bf16x8*)(Al + (wm + mi * 16 + lm) * 32 + lq * 8);
#pragma unroll
    for (int ni = 0; ni < 4; ++ni)
      bfr[ni] = *(const bf16x8*)(Bl + (wn + ni * 16 + lm) * 32 + lq * 8);
#pragma unroll
    for (int mi = 0; mi < 4; ++mi)
#pragma unroll
      for (int ni = 0; ni < 4; ++ni)
        acc[mi][ni] = __builtin_amdgcn_mfma_f32_16x16x32_bf16(
            af[mi], bfr[ni], acc[mi][ni], 0, 0, 0);
    __syncthreads();
  }

  // epilogue: C/D layout col=lane&15, row=(lane>>4)*4+r  (m89/m91 verified)
  const int r0 = lq * 4;
#pragma unroll
  for (int mi = 0; mi < 4; ++mi)
#pragma unroll
    for (int ni = 0; ni < 4; ++ni)
#pragma unroll
      for (int r = 0; r < 4; ++r) {
        const size_t row = (size_t)(m0 + wm + mi * 16 + r0 + r);
        const size_t col = (size_t)(n0 + wn + ni * 16 + lm);
        if (Cf) Cf[row * N + col] = acc[mi][ni][r];
        else    Cb[row * N + col] = (__bf16)acc[mi][ni][r];
      }
}

// ---------------------------------------------------------------------------
// qk RMS-norm + 3D RoPE + layout transform.
// ---------------------------------------------------------------------------
static __device__ __forceinline__ float rope_one(float v, float p, int d,
                                                 const float* c3) {
  const int a  = d >> 5;        // which of 3 coord axes (d3=32)
  const int j  = d & 31;
  const int jj = j & 15;        // half=16
  const float invf = fexp2((float)jj * -0.8304820237218406f);
  const float ang  = c3[a] * invf;
  float sn, cs;
  __sincosf(ang, &sn, &cs);
  return (j < 16) ? (v * cs - p * sn) : (v * cs + p * sn);
}

__global__ __launch_bounds__(256) void normrope_kernel(
    const __bf16* __restrict__ qkv, const float* __restrict__ coords,
    const int* __restrict__ ttype, const float* __restrict__ qsc,
    const float* __restrict__ ksc, __bf16* __restrict__ qo,
    __bf16* __restrict__ ko, __bf16* __restrict__ vo) {
  const int l   = threadIdx.x & 63;
  const int w   = threadIdx.x >> 6;
  const int rid = blockIdx.x * 4 + w;       // (b*T+t)*H + h
  const int h   = rid & (NH - 1);
  const int bt  = rid >> 4;
  const int t   = bt & (NT - 1);
  const int b   = bt >> 11;                 // T = 2048
  const __bf16* base = qkv + (size_t)bt * NQKV + h * ND;
  const float*  c3   = coords + (size_t)bt * 3;
  const bool rope    = ttype[bt] > 0;
  const size_t bh    = (size_t)(b * NH + h);

  // ---- q ----
  {
    float x0 = (float)base[l];
    float x1 = (l < 32) ? (float)base[64 + l] : 0.f;
    float ss = x0 * x0 + x1 * x1;
#pragma unroll
    for (int off = 1; off < 64; off <<= 1) ss += __shfl_xor(ss, off, 64);
    const float rn = rsqrtf(ss * (1.f / 96.f) + 1e-6f);
    x0 *= rn * qsc[l];
    if (l < 32) x1 *= rn * qsc[64 + l];
    const float p0 = __shfl_xor(x0, 16, 64);
    const float p1 = __shfl_xor(x1, 16, 64);
    if (rope) {
      x0 = rope_one(x0, p0, l, c3);
      if (l < 32) x1 = rope_one(x1, p1, 64 + l, c3);
    }
    __bf16* dst = qo + (bh * NT + t) * ND;
    dst[l] = (__bf16)x0;
    if (l < 32) dst[64 + l] = (__bf16)x1;
  }
  // ---- k ----
  {
    float x0 = (float)base[NC + l];
    float x1 = (l < 32) ? (float)base[NC + 64 + l] : 0.f;
    float ss = x0 * x0 + x1 * x1;
#pragma unroll
    for (int off = 1; off < 64; off <<= 1) ss += __shfl_xor(ss, off, 64);
    const float rn = rsqrtf(ss * (1.f / 96.f) + 1e-6f);
    x0 *= rn * ksc[l];
    if (l < 32) x1 *= rn * ksc[64 + l];
    const float p0 = __shfl_xor(x0, 16, 64);
    const float p1 = __shfl_xor(x1, 16, 64);
    if (rope) {
      x0 = rope_one(x0, p0, l, c3);
      if (l < 32) x1 = rope_one(x1, p1, 64 + l, c3);
    }
    __bf16* dst = ko + (bh * NT + t) * ND;
    dst[l] = (__bf16)x0;
    if (l < 32) dst[64 + l] = (__bf16)x1;
  }
  // ---- v (transpose only) ----
  {
    vo[(bh * ND + l) * NT + t] = base[2 * NC + l];
    if (l < 32) vo[(bh * ND + 64 + l) * NT + t] = base[2 * NC + 64 + l];
  }
}

// ---------------------------------------------------------------------------
// Flash attention with LDS-staged K/V, fixed-max softmax.
// q,k: (B,H,T,D) bf16; vT: (B,H,D,T) bf16; out: (B,T,H,D)=(B*T,C) bf16.
// Grid (8, B*H), block = 8 waves (512 thr). Wave w owns two mirrored 16-row
// frags: q0L = qp*128+w*16, q0H = (15-qp)*128+w*16 -> uniform block work.
// Per 32-key tile: stage K(6KB)+vT(6KB) -> LDS via g2lds16 with source-addr
// permutation so LDS is in fragment-read order (each frag read = 64 lanes
// reading a contiguous 1KB span; conflict-free). Double-buffered; stage for
// kt+1 issued after the barrier -> overlaps compute of kt.
// ---------------------------------------------------------------------------
static __device__ __forceinline__ void attn_tile(
    const bf16x8 (&aq)[3], const bf16x8 (&bk)[2][3], int q0r, int n0,
    int lm, int lq, f32x4& lsum, __bf16* pbase /* 16 rows x 40 */) {
  f32x4 s[2];
#pragma unroll
  for (int nt = 0; nt < 2; ++nt) {
    f32x4 a = {};
#pragma unroll
    for (int c = 0; c < 3; ++c)
      a = __builtin_amdgcn_mfma_f32_16x16x32_bf16(aq[c], bk[nt][c], a, 0, 0, 0);
    s[nt] = a;
  }
  if (n0 + 31 > q0r) {   // diagonal-straddling tile: causal mask
#pragma unroll
    for (int nt = 0; nt < 2; ++nt)
#pragma unroll
      for (int r = 0; r < 4; ++r)
        if (n0 + nt * 16 + lm > q0r + lq * 4 + r) s[nt][r] = -1e30f;
  }
  const float cl = 0.10206207261596575f * 1.4426950408889634f;
#pragma unroll
  for (int nt = 0; nt < 2; ++nt)
#pragma unroll
    for (int r = 0; r < 4; ++r)
      s[nt][r] = fexp2((s[nt][r] - 96.0f) * cl);
#pragma unroll
  for (int r = 0; r < 4; ++r) lsum[r] += s[0][r] + s[1][r];
#pragma unroll
  for (int nt = 0; nt < 2; ++nt)
#pragma unroll
    for (int r = 0; r < 4; ++r)
      pbase[(lq * 4 + r) * 40 + nt * 16 + lm] = (__bf16)s[nt][r];
}

__global__ __launch_bounds__(512) void attn_fwd2(
    const __bf16* __restrict__ q, const __bf16* __restrict__ k,
    const __bf16* __restrict__ vt, __bf16* __restrict__ out) {
  __shared__ __align__(16) char KV[2][12288];        // [buf][K 6KB | V 6KB]
  __shared__ __align__(16) __bf16 plds[8][2][16][40];
  const int tid = threadIdx.x;
  const int l   = tid & 63;
  const int w   = tid >> 6;          // 0..7
  const int bh  = blockIdx.y;
  const int qp  = blockIdx.x;        // 0..7
  const int lm  = l & 15;
  const int lq  = l >> 4;
  const int q0L = qp * 128 + w * 16;
  const int q0H = (15 - qp) * 128 + w * 16;
  const int nktLw = qp * 4 + (w >> 1) + 1;          // causal tiles, frag L
  const int nktHw = (15 - qp) * 4 + (w >> 1) + 1;   // causal tiles, frag H
  const int nkt   = (15 - qp) * 4 + 4;              // block loop bound
  const __bf16* qh = q  + (size_t)bh * NT * ND;
  const __bf16* kh = k  + (size_t)bh * NT * ND;
  const __bf16* vh = vt + (size_t)bh * ND * NT;
  __bf16* pbL = &plds[w][0][0][0];
  __bf16* pbH = &plds[w][1][0][0];

  // stage tile at key n0 into buf. LDS K layout: chunk (nt*3+c)*64 + lm*4+lq
  // holds K[n0+nt*16+lm][c*32+lq*8 ..+7]; V chunk dt*64+lm*4+lq holds
  // vT[dt*16+lm][n0+lq*8 ..+7]. Wave-uniform LDS bases, all lanes active.
  auto stage = [&](int n0, char* buf) {
    if (w < 6) {
      const int nt = w / 3, c = w - nt * 3;
      g2lds16(kh + (size_t)(n0 + nt * 16 + (l >> 2)) * ND + c * 32 + (l & 3) * 8,
              buf + w * 1024);
    } else {
      const int v = w - 6;
      g2lds16(vh + (size_t)(v * 16 + (l >> 2)) * NT + n0 + (l & 3) * 8,
              buf + 6144 + v * 1024);
    }
    if (w < 4) {
      const int v = 2 + w;
      g2lds16(vh + (size_t)(v * 16 + (l >> 2)) * NT + n0 + (l & 3) * 8,
              buf + 6144 + v * 1024);
    }
  };

  bf16x8 aqL[3], aqH[3];
#pragma unroll
  for (int c = 0; c < 3; ++c) {
    aqL[c] = *(const bf16x8*)(qh + (size_t)(q0L + lm) * ND + c * 32 + lq * 8);
    aqH[c] = *(const bf16x8*)(qh + (size_t)(q0H + lm) * ND + c * 32 + lq * 8);
  }

  f32x4 oL[6] = {}, oH[6] = {};
  f32x4 lsL = {}, lsH = {};
  const int ji = (lm * 4 + lq) * 16;   // this lane's chunk byte offset

  stage(0, KV[0]);
  for (int kt = 0; kt < nkt; ++kt) {
    __syncthreads();                   // drains stage(kt); all waves done kt-1
    if (kt + 1 < nkt) stage((kt + 1) * 32, KV[(kt + 1) & 1]);
    const char* Kc = KV[kt & 1];
    const char* Vc = KV[kt & 1] + 6144;
    const int n0 = kt * 32;
    bf16x8 bk[2][3];
#pragma unroll
    for (int nt = 0; nt < 2; ++nt)
#pragma unroll
      for (int c = 0; c < 3; ++c)
        bk[nt][c] = *(const bf16x8*)(Kc + (nt * 3 + c) * 1024 + ji);
    const bool doL = kt < nktLw;       // wave-uniform
    const bool doH = kt < nktHw;
    if (doL) attn_tile(aqL, bk, q0L, n0, lm, lq, lsL, pbL);
    if (doH) attn_tile(aqH, bk, q0H, n0, lm, lq, lsH, pbH);
    bf16x8 apL = {}, apH = {};
    if (doL) apL = *(const bf16x8*)(pbL + lm * 40 + lq * 8);
    if (doH) apH = *(const bf16x8*)(pbH + lm * 40 + lq * 8);
#pragma unroll
    for (int dt = 0; dt < 6; ++dt) {
      bf16x8 bv = *(const bf16x8*)(Vc + dt * 1024 + ji);
      if (doL) oL[dt] = __builtin_amdgcn_mfma_f32_16x16x32_bf16(apL, bv, oL[dt], 0, 0, 0);
      if (doH) oH[dt] = __builtin_amdgcn_mfma_f32_16x16x32_bf16(apH, bv, oH[dt], 0, 0, 0);
    }
  }

  // epilogue: out[(b*T+t), h*96+d] for both frags
  const int b = bh >> 4, h = bh & 15;
#pragma unroll
  for (int f = 0; f < 2; ++f) {
    const f32x4* o = f ? oH : oL;
    const f32x4& ls = f ? lsH : lsL;
    const int q0 = f ? q0H : q0L;
    float rl[4];
#pragma unroll
    for (int r = 0; r < 4; ++r) {
      float v = ls[r];
#pragma unroll
      for (int off = 1; off < 16; off <<= 1) v += __shfl_xor(v, off, 64);
      rl[r] = 1.f / v;
    }
#pragma unroll
    for (int dt = 0; dt < 6; ++dt)
#pragma unroll
      for (int r = 0; r < 4; ++r) {
        const int t = q0 + lq * 4 + r;
        out[((size_t)(b * NT + t)) * NC + h * ND + dt * 16 + lm] =
            (__bf16)(o[dt][r] * rl[r]);
      }
  }
}

// ---------------------------------------------------------------------------
// workspace layout (bytes); attn-out aliases xb (dead after GEMM1)
// ---------------------------------------------------------------------------
static constexpr size_t OFF_XB   = 0;          // 12,582,912  (also attn out)
static constexpr size_t OFF_WQKV = 12582912;   // 14,155,776
static constexpr size_t OFF_WOUT = 26738688;   //  4,718,592
static constexpr size_t OFF_QKV  = 31457280;   // 37,748,736
static constexpr size_t OFF_Q    = 69206016;   // 12,582,912
static constexpr size_t OFF_K    = 81788928;   // 12,582,912
static constexpr size_t OFF_VT   = 94371840;   // 12,582,912  -> end 106,954,752

extern "C" void kernel_launch(void* const* d_in, const int* in_sizes, int n_in,
                              void* d_out, int out_size, void* d_ws,
                              size_t ws_size, hipStream_t stream) {
  const float* x      = (const float*)d_in[0];
  const float* coords = (const float*)d_in[1];
  const int*   ttype  = (const int*)d_in[2];
  const float* wqkv   = (const float*)d_in[3];
  const float* wout   = (const float*)d_in[4];
  const float* qs     = (const float*)d_in[5];
  const float* ks     = (const float*)d_in[6];

  char* ws = (char*)d_ws;
  __bf16* xb    = (__bf16*)(ws + OFF_XB);
  __bf16* wqkvb = (__bf16*)(ws + OFF_WQKV);
  __bf16* woutb = (__bf16*)(ws + OFF_WOUT);
  __bf16* qkvb  = (__bf16*)(ws + OFF_QKV);
  __bf16* qb    = (__bf16*)(ws + OFF_Q);
  __bf16* kb    = (__bf16*)(ws + OFF_K);
  __bf16* vtb   = (__bf16*)(ws + OFF_VT);
  __bf16* attnb = (__bf16*)(ws + OFF_XB);   // alias

  // 1. fp32 -> bf16 conversions
  {
    const int n4x = NM * NC / 4;            // 1,572,864
    const int n4w = NQKV * NC / 4;          // 1,769,472
    const int n4o = NC * NC / 4;            //   589,824
    cvt_f32_bf16<<<(n4x + 255) / 256, 256, 0, stream>>>(
        (const float4*)x, (bf16x4*)xb, n4x);
    cvt_f32_bf16<<<(n4w + 255) / 256, 256, 0, stream>>>(
        (const float4*)wqkv, (bf16x4*)wqkvb, n4w);
    cvt_f32_bf16<<<(n4o + 255) / 256, 256, 0, stream>>>(
        (const float4*)wout, (bf16x4*)woutb, n4o);
  }
  // 2. qkv = x @ W_qkv^T  (bf16 out)
  gemm_bt<<<dim3(NQKV / 128, NM / 128), 256, 0, stream>>>(
      xb, wqkvb, nullptr, qkvb, NM, NQKV, NC);
  // 3. qk-norm + rope + v-transpose
  normrope_kernel<<<(NB * NT * NH) / 4, 256, 0, stream>>>(
      qkvb, coords, ttype, qs, ks, qb, kb, vtb);
  // 4. causal attention (LDS-staged K/V, mirrored q-pairs)
  attn_fwd2<<<dim3(8, NB * NH), 512, 0, stream>>>(qb, kb, vtb, attnb);
  // 5. out = attn @ W_out^T (fp32 out)
  gemm_bt<<<dim3(NC / 128, NM / 128), 256, 0, stream>>>(
      attnb, woutb, (float*)d_out, nullptr, NM, NC, NC);
}